// Round 4
// baseline (219.326 us; speedup 1.0000x reference)
//
#include <hip/hip_runtime.h>
#include <math.h>

// LorentzNotGroupNorm, MI355X. x:(64,3136,128) fp32, groups=8.
// Group = 8 consecutive pixels x 128 ch = 4KB; one wave per group (2 groups/wave).
//
// pass1 NEW layout (channel-major, zero LDS): lane = (par=lane>>5, c=lane&31).
// Contiguous float4 load j gives lane channels 4c..4c+3 of pixel (2j+par) --
// the compute layout IS the load layout (no fold, no transpose, no LDS).
//   avg: in-register over 4 pixels + one xor-32 shuffle.
//   per-pixel dots: 5-stage butterfly (masks 1,2,4,8,16) within parity halves.
//   x_T = sc*y + k*avg + coef*e0; nvar from verified xt_norm algebra;
//   second loop reduces only PE,PB.
// cache per group: avg[128] + 8 pixel-bundles{sc,k,coef,PE,PB,XT0,0,0}.
// finalize: var mean + global <beta,beta>_L. pass2: fully elementwise,
// wave-contiguous (unchanged, near its memory floor).

constexpr int S_GROUPS = 392;              // spatial groups per batch
constexpr int N_GROUPS = 64 * S_GROUPS;    // 25088
constexpr int CSTRIDE = 192;               // floats/group: 128 avg + 8*8 bundle

__device__ __forceinline__ float dot4(const float4 a, const float4 b) {
  return fmaf(a.x, b.x, fmaf(a.y, b.y, fmaf(a.z, b.z, a.w * b.w)));
}

__device__ __forceinline__ void rsum8x3(float& a, float& b, float& c) {
#pragma unroll
  for (int m = 1; m <= 4; m <<= 1) {
    a += __shfl_xor(a, m, 64);
    b += __shfl_xor(b, m, 64);
    c += __shfl_xor(c, m, 64);
  }
}

// One group in channel-major layout. v[j] = channels 4c..4c+3 of pixel 2j+par.
__device__ __forceinline__ void core_cp(
    const float4 v[4], const float4 gm4, const float4 bt4, const float4 g24,
    const float4 bg4, float gm0, float bt0, int c, int par,
    float* __restrict__ gc, float* __restrict__ var_part, int b, int s) {
  // pixel-mean: sum own 4 pixels + partner parity half
  float4 sum;
  sum.x = v[0].x + v[1].x + v[2].x + v[3].x;
  sum.y = v[0].y + v[1].y + v[2].y + v[3].y;
  sum.z = v[0].z + v[1].z + v[2].z + v[3].z;
  sum.w = v[0].w + v[1].w + v[2].w + v[3].w;
  float4 avg;
  avg.x = (sum.x + __shfl_xor(sum.x, 32, 64)) * 0.125f;
  avg.y = (sum.y + __shfl_xor(sum.y, 32, 64)) * 0.125f;
  avg.z = (sum.z + __shfl_xor(sum.z, 32, 64)) * 0.125f;
  avg.w = (sum.w + __shfl_xor(sum.w, 32, 64)) * 0.125f;
  if (par == 0)  // coalesced 512B avg write
    *reinterpret_cast<float4*>(gc + 4 * c) = avg;

  // first dots (pure Euclid over this lane's 4 channels)
  float aa = dot4(avg, avg);
  float ya[4], yy[4];
#pragma unroll
  for (int j = 0; j < 4; ++j) {
    ya[j] = dot4(avg, v[j]);
    yy[j] = dot4(v[j], v[j]);
  }
  // butterfly over channel lanes (within parity half): 9 values x 5 stages
#pragma unroll
  for (int m = 1; m <= 16; m <<= 1) {
    aa += __shfl_xor(aa, m, 64);
#pragma unroll
    for (int j = 0; j < 4; ++j) {
      ya[j] += __shfl_xor(ya[j], m, 64);
      yy[j] += __shfl_xor(yy[j], m, 64);
    }
  }
  const float avg0 = __shfl(avg.x, 0, 64);  // channel 0 of avg
  float y0[4];
#pragma unroll
  for (int j = 0; j < 4; ++j)
    y0[j] = __shfl(v[j].x, par * 32, 64);   // channel 0 of pixel 2j+par

  // per-pixel scalar chains (independent across j -> good ILP)
  const float aaL = aa - 2.f * avg0 * avg0;
  const float rden = rsqrtf(fmaxf(-aaL, 1e-8f));
  const float mean0 = rden * avg0;
  float scv[4], kv[4], cfv[4], xt0v[4];
#pragma unroll
  for (int j = 0; j < 4; ++j) {
    const float yaL = ya[j] - 2.f * avg0 * y0[j];
    const float yyL = yy[j] - 2.f * y0[j] * y0[j];
    const float a_raw = -yaL * rden;
    const float alpha = fmaxf(a_raw, 1.f + 1e-7f);
    const float t = alpha - 1.f;
    const float dist = log1pf(t + sqrtf(t * (alpha + 1.f)));  // arccosh
    const float inn = fmaxf(yyL + 2.f * alpha * a_raw - alpha * alpha, 1e-8f);
    const float sc = dist * rsqrtf(inn);
    const float am = alpha * rden;
    const float v0 = sc * (y0[j] - am * avg0);
    const float coef = -v0 / (1.f + mean0);
    const float k = coef * rden - sc * am;
    scv[j] = sc; kv[j] = k; cfv[j] = coef;
    // ||x_T||_E from Euclid dots (verified xt_norm algebra)
    const float T0 = fmaf(sc, y0[j], k * avg0);
    const float na = sc * sc * yy[j] + k * k * aa + 2.f * sc * k * ya[j] +
                     coef * coef + 2.f * coef * T0;
    xt0v[j] = T0 + coef;
    const float nvar = sqrtf(fmaxf(na, 0.f));
    if (c == j)
      var_part[(size_t)(b * 8 + 2 * j + par) * S_GROUPS + s] = nvar;
  }

  // second loop: xt per channel, reduce PE (gamma^2-weighted) and PB (beta*gamma)
  float pe[4], pb[4];
#pragma unroll
  for (int j = 0; j < 4; ++j) {
    float4 xt;
    xt.x = fmaf(scv[j], v[j].x, kv[j] * avg.x);
    xt.y = fmaf(scv[j], v[j].y, kv[j] * avg.y);
    xt.z = fmaf(scv[j], v[j].z, kv[j] * avg.z);
    xt.w = fmaf(scv[j], v[j].w, kv[j] * avg.w);
    if (c == 0) xt.x += cfv[j];
    pe[j] = g24.x * xt.x * xt.x + g24.y * xt.y * xt.y + g24.z * xt.z * xt.z +
            g24.w * xt.w * xt.w;
    pb[j] = dot4(bg4, xt);
  }
#pragma unroll
  for (int m = 1; m <= 16; m <<= 1) {
#pragma unroll
    for (int j = 0; j < 4; ++j) {
      pe[j] += __shfl_xor(pe[j], m, 64);
      pb[j] += __shfl_xor(pb[j], m, 64);
    }
  }
#pragma unroll
  for (int j = 0; j < 4; ++j) {
    const float PB = pb[j] - 2.f * bt0 * (gm0 * xt0v[j]);  // Lorentz time sign
    if (c == j) {
      const int pix = 2 * j + par;
      *reinterpret_cast<float4*>(gc + 128 + pix * 8) =
          make_float4(scv[j], kv[j], cfv[j], pe[j]);
      *reinterpret_cast<float4*>(gc + 128 + pix * 8 + 4) =
          make_float4(PB, xt0v[j], 0.f, 0.f);
    }
  }
}

__global__ __launch_bounds__(256) void lngn_pass1(
    const float* __restrict__ x, const float* __restrict__ gamma,
    const float* __restrict__ beta, float* __restrict__ var_part,
    float* __restrict__ cache) {
  const int w = threadIdx.x >> 6, lane = threadIdx.x & 63;
  const int c = lane & 31, par = lane >> 5;
  const int wid0 = (blockIdx.x * 4 + w) * 2;   // 2 groups per wave
  const float* g0 = x + (size_t)wid0 * 1024;

  // wave-contiguous loads; layout directly matches compute layout
  float4 vA[4], vB[4];
#pragma unroll
  for (int j = 0; j < 4; ++j) {
    vA[j] = *reinterpret_cast<const float4*>(g0 + j * 256 + 4 * lane);
    vB[j] = *reinterpret_cast<const float4*>(g0 + 1024 + j * 256 + 4 * lane);
  }
  const float4 gm4 = *reinterpret_cast<const float4*>(gamma + 4 * c);
  const float4 bt4 = *reinterpret_cast<const float4*>(beta + 4 * c);
  float4 g24, bg4;
  g24.x = gm4.x * gm4.x; g24.y = gm4.y * gm4.y;
  g24.z = gm4.z * gm4.z; g24.w = gm4.w * gm4.w;
  bg4.x = bt4.x * gm4.x; bg4.y = bt4.y * gm4.y;
  bg4.z = bt4.z * gm4.z; bg4.w = bt4.w * gm4.w;
  const float gm0 = gamma[0], bt0 = beta[0];

  const int b = wid0 / S_GROUPS;
  const int s = wid0 - b * S_GROUPS;   // wid0 even, 392 even => wid0+1 same b
  core_cp(vA, gm4, bt4, g24, bg4, gm0, bt0, c, par,
          cache + (size_t)wid0 * CSTRIDE, var_part, b, s);
  core_cp(vB, gm4, bt4, g24, bg4, gm0, bt0, c, par,
          cache + (size_t)(wid0 + 1) * CSTRIDE, var_part, b, s + 1);
}

__global__ __launch_bounds__(256) void lngn_finalize(
    const float* __restrict__ var_part, const float* __restrict__ beta,
    float* __restrict__ var_out) {
  const int wv = (int)((blockIdx.x * 256 + threadIdx.x) >> 6);  // 0..511 = b*8+p
  const int lane = threadIdx.x & 63;
  const float* base = var_part + (size_t)wv * S_GROUPS;
  float s = 0.f;
  for (int s0 = lane; s0 < S_GROUPS; s0 += 64) s += base[s0];
#pragma unroll
  for (int m = 32; m >= 1; m >>= 1) s += __shfl_xor(s, m, 64);
  if (lane == 0) var_out[wv] = s * (1.f / (float)S_GROUPS);

  // one wave additionally computes the global scalar <beta,beta>_L
  if (blockIdx.x == 0 && threadIdx.x < 64) {
    const int l = threadIdx.x;
    float b0v = beta[2 * l], b1v = beta[2 * l + 1];
    float tsum = b0v * b0v + b1v * b1v;
    if (l == 0) tsum -= 2.f * b0v * b0v;
#pragma unroll
    for (int m = 32; m >= 1; m >>= 1) tsum += __shfl_xor(tsum, m, 64);
    if (l == 0) var_out[512] = tsum;
  }
}

__global__ __launch_bounds__(256) void lngn_pass2(
    const float* __restrict__ x, const float* __restrict__ gamma,
    const float* __restrict__ beta, const float* __restrict__ var,
    const float* __restrict__ cache, float* __restrict__ out) {
  const int w = threadIdx.x >> 6, lane = threadIdx.x & 63;
  const int wid = blockIdx.x * 4 + w;
  const float* xb = x + (size_t)wid * 1024;
  const float* gc = cache + (size_t)wid * CSTRIDE;
  const int cl = lane & 31;   // channel-quad index: channels 4*cl..+3
  const int par = lane >> 5;  // pixel parity

  // wave-contiguous loads: instruction j covers bytes [j*1024 + lane*16)
  float4 xv[4];
#pragma unroll
  for (int j = 0; j < 4; ++j)
    xv[j] = *reinterpret_cast<const float4*>(xb + j * 256 + 4 * lane);
  const float4 av = *reinterpret_cast<const float4*>(gc + 4 * cl);
  const float4 gm4 = *reinterpret_cast<const float4*>(gamma + 4 * cl);
  const float4 bt4 = *reinterpret_cast<const float4*>(beta + 4 * cl);

  // per-pixel A-chain (lane computes pixel lane&7; 8-fold redundant)
  const int pix = lane & 7;
  const float4 s0 = *reinterpret_cast<const float4*>(gc + 128 + pix * 8);
  const float4 s1v = *reinterpret_cast<const float4*>(gc + 128 + pix * 8 + 4);
  const float sc = s0.x, kk = s0.y, coef = s0.z, PE = s0.w;
  const float PB = s1v.x, XT0 = s1v.y;
  const int b = wid / S_GROUPS;
  const float varv = var[b * 8 + pix];
  const float pbb = var[512];
  const float bt0 = beta[0], gm0 = gamma[0];

  const float is1 = 1.f / (varv + 1e-5f);
  const float pe = is1 * is1 * PE;
  const float pb = is1 * PB;
  const float u0 = is1 * gm0 * XT0;
  const float n = sqrtf(pe);
  const float scl = fminf(1.f, 10.f / fmaxf(n, 1e-8f));
  const float c2 = scl * pb / (1.f + bt0);
  const float uuL = pe - 2.f * u0 * u0;
  const float innw = scl * scl * uuL + 2.f * scl * c2 * (pb - u0) +
                     c2 * c2 * (pbb - 2.f * bt0 - 1.f);
  const float nrm = sqrtf(fmaxf(innw, 1e-8f));
  const float e = expf(nrm), ie = 1.f / e;
  const float chv = 0.5f * (e + ie);
  const float isn = (0.5f * (e - ie)) / nrm;
  const float A1 = chv + isn * c2;        // * beta_i
  const float Cu = isn * scl * is1;
  const float A2 = Cu * sc;               // * gamma_i * x_i
  const float A3 = Cu * kk;               // * gamma_i * avg_i
  const float A4 = fmaf(Cu * gm0, coef, isn * c2);  // += at channel 0

  float* ob = out + (size_t)wid * 1024;
#pragma unroll
  for (int j = 0; j < 4; ++j) {
    const int sp = 2 * j + par;           // pixel of this lane's j-th quad
    const float a1 = __shfl(A1, sp, 64);
    const float a2 = __shfl(A2, sp, 64);
    const float a3 = __shfl(A3, sp, 64);
    const float a4 = __shfl(A4, sp, 64);
    float4 o4;
    o4.x = fmaf(a1, bt4.x, gm4.x * fmaf(a2, xv[j].x, a3 * av.x));
    o4.y = fmaf(a1, bt4.y, gm4.y * fmaf(a2, xv[j].y, a3 * av.y));
    o4.z = fmaf(a1, bt4.z, gm4.z * fmaf(a2, xv[j].z, a3 * av.z));
    o4.w = fmaf(a1, bt4.w, gm4.w * fmaf(a2, xv[j].w, a3 * av.w));
    if (cl == 0) o4.x += a4;              // channel 0 of this pixel
    *reinterpret_cast<float4*>(ob + j * 256 + 4 * lane) = o4;
  }
}

extern "C" void kernel_launch(void* const* d_in, const int* in_sizes, int n_in,
                              void* d_out, int out_size, void* d_ws,
                              size_t ws_size, hipStream_t stream) {
  const float* x = (const float*)d_in[0];
  const float* gamma = (const float*)d_in[1];
  const float* beta = (const float*)d_in[2];
  float* out = (float*)d_out;
  float* var_part = (float*)d_ws;                      // 512*392 floats
  float* var_final = var_part + (size_t)N_GROUPS * 8;  // 513 floats (last=<b,b>_L)
  float* cache = var_part + 201472;                    // 16B-aligned, ~19.3 MB

  lngn_pass1<<<N_GROUPS / 8, 256, 0, stream>>>(x, gamma, beta, var_part, cache);
  lngn_finalize<<<128, 256, 0, stream>>>(var_part, beta, var_final);
  lngn_pass2<<<N_GROUPS / 4, 256, 0, stream>>>(x, gamma, beta, var_final, cache,
                                               out);
}

// Round 5
// 209.727 us; speedup vs baseline: 1.0458x; 1.0458x over previous
//
#include <hip/hip_runtime.h>
#include <math.h>

// LorentzNotGroupNorm, MI355X. x:(64,3136,128) fp32, groups=8.
// Group = 8 consecutive pixels x 128 ch = 4KB; one wave per 2 groups.
// pass1 (p,q layout; lane = 8*p+q, 16 ch/lane): ONE interleaved spine for
// both groups:
//   fold A+B -> one fence -> fused dot loop (8 accs/group, incl gamma-weighted
//   dots) -> one rsum (16 values x 3 stages) -> 2 independent scalar chains.
// Second vector loop eliminated algebraically:
//   pe = sc^2*Gyy + k^2*Gaa + 2sc*k*Gya + g0^2*coef*(coef+2*T0)
//   pb = sc*By + k*Ba - b0g0*(2*T0+coef)
//   na = sc^2*yy + k^2*aa + 2sc*k*ya + coef^2 + 2*coef*T0   (R4-verified)
// cache per group: avg[128] + 8 pixel-bundles{sc,k,coef,PE,PB,XT0,0,0}.
// pass2: fully elementwise, wave-contiguous (unchanged; near memory floor).

constexpr int S_GROUPS = 392;              // spatial groups per batch
constexpr int N_GROUPS = 64 * S_GROUPS;    // 25088
constexpr int CSTRIDE = 192;               // floats/group: 128 avg + 8*8 bundle

__device__ __forceinline__ void wave_lds_fence() {
  __asm__ volatile("" ::: "memory");
  __builtin_amdgcn_wave_barrier();
  __asm__ volatile("" ::: "memory");
}

// Pixel-mean fold over lane bits {32,16,8}; lane (p,q) ends with mean
// channels {16q+2p, 16q+2p+1} in (c0,c1).
__device__ __forceinline__ void fold_mean(const float v[16], int lane,
                                          float& c0, float& c1) {
  float a8[8];
  const bool h5 = (lane & 32) != 0;
#pragma unroll
  for (int i = 0; i < 8; ++i) {
    float kp = h5 ? v[i + 8] : v[i];
    float sd = h5 ? v[i] : v[i + 8];
    a8[i] = kp + __shfl_xor(sd, 32, 64);
  }
  float a4[4];
  const bool h4 = (lane & 16) != 0;
#pragma unroll
  for (int i = 0; i < 4; ++i) {
    float kp = h4 ? a8[i + 4] : a8[i];
    float sd = h4 ? a8[i] : a8[i + 4];
    a4[i] = kp + __shfl_xor(sd, 16, 64);
  }
  const bool h3 = (lane & 8) != 0;
  float kp0 = h3 ? a4[2] : a4[0], sd0 = h3 ? a4[0] : a4[2];
  float kp1 = h3 ? a4[3] : a4[1], sd1 = h3 ? a4[1] : a4[3];
  c0 = (kp0 + __shfl_xor(sd0, 8, 64)) * 0.125f;
  c1 = (kp1 + __shfl_xor(sd1, 8, 64)) * 0.125f;
}

struct Dots {
  float pa, pd, py, Gyy, Gya, Gaa, By, Ba;  // all plain-Euclid sums
};

// scalar chain + epilogue for one group; writes bundle + nvar (q==0 lanes).
__device__ __forceinline__ void chain_ep(const Dots& d, float y0, float avg0,
                                         float gm0, float b0g0, int q, int p,
                                         float* __restrict__ gc,
                                         float* __restrict__ var_part,
                                         size_t vidx) {
  const float aaL = d.pa - 2.f * avg0 * avg0;
  const float rden = rsqrtf(fmaxf(-aaL, 1e-8f));
  const float mean0 = rden * avg0;
  const float yaL = d.pd - 2.f * avg0 * y0;
  const float yyL = d.py - 2.f * y0 * y0;
  const float a_raw = -yaL * rden;
  const float alpha = fmaxf(a_raw, 1.f + 1e-7f);
  const float t = alpha - 1.f;
  const float dist = log1pf(t + sqrtf(t * (alpha + 1.f)));   // arccosh
  const float inn = fmaxf(yyL + 2.f * alpha * a_raw - alpha * alpha, 1e-8f);
  const float sc = dist * rsqrtf(inn);
  const float am = alpha * rden;
  const float v0 = sc * (y0 - am * avg0);
  const float coef = -v0 / (1.f + mean0);
  const float k = coef * rden - sc * am;
  const float T0 = fmaf(sc, y0, k * avg0);
  // ||x_T||_E (verified algebra, Euclid dots)
  const float na = sc * sc * d.py + k * k * d.pa + 2.f * sc * k * d.pd +
                   coef * coef + 2.f * coef * T0;
  const float nvar = sqrtf(fmaxf(na, 0.f));
  // PE = ||gamma*x_T||^2_E via gamma-weighted dots + ch0 coef correction
  const float pe = sc * sc * d.Gyy + k * k * d.Gaa + 2.f * sc * k * d.Gya +
                   gm0 * gm0 * coef * (coef + 2.f * T0);
  // PB = <beta, gamma*x_T>_L
  const float pb = fmaf(sc, d.By, k * d.Ba) - b0g0 * (2.f * T0 + coef);
  const float XT0 = T0 + coef;
  if (q == 0) {
    *reinterpret_cast<float4*>(gc + 128 + p * 8) = make_float4(sc, k, coef, pe);
    *reinterpret_cast<float4*>(gc + 128 + p * 8 + 4) =
        make_float4(pb, XT0, 0.f, 0.f);
    var_part[vidx] = nvar;
  }
}

__global__ __launch_bounds__(256) void lngn_pass1(
    const float* __restrict__ x, const float* __restrict__ gamma,
    const float* __restrict__ beta, float* __restrict__ var_part,
    float* __restrict__ cache) {
  __shared__ float sm[4][2][128];
  const int w = threadIdx.x >> 6, lane = threadIdx.x & 63;
  const int p = lane >> 3, q = lane & 7;
  const int wid0 = (blockIdx.x * 4 + w) * 2;   // 2 groups per wave
  const float* b0 = x + (size_t)wid0 * 1024 + p * 128 + q * 16;
  float* gcA = cache + (size_t)wid0 * CSTRIDE;
  float* gcB = gcA + CSTRIDE;

  float vA[16], vB[16], gm[16], bt[16];
#pragma unroll
  for (int j = 0; j < 4; ++j) {
    *reinterpret_cast<float4*>(&vA[4 * j]) =
        *reinterpret_cast<const float4*>(b0 + 4 * j);
    *reinterpret_cast<float4*>(&vB[4 * j]) =
        *reinterpret_cast<const float4*>(b0 + 1024 + 4 * j);
    *reinterpret_cast<float4*>(&gm[4 * j]) =
        *reinterpret_cast<const float4*>(gamma + q * 16 + 4 * j);
    *reinterpret_cast<float4*>(&bt[4 * j]) =
        *reinterpret_cast<const float4*>(beta + q * 16 + 4 * j);
  }

  // ---- fold both groups (independent shuffle chains -> 2x ILP) ----
  float c0A, c1A, c0B, c1B;
  fold_mean(vA, lane, c0A, c1A);
  fold_mean(vB, lane, c0B, c1B);
  *reinterpret_cast<float2*>(&sm[w][0][q * 16 + p * 2]) = make_float2(c0A, c1A);
  *reinterpret_cast<float2*>(&sm[w][1][q * 16 + p * 2]) = make_float2(c0B, c1B);
  *reinterpret_cast<float2*>(&gcA[q * 16 + p * 2]) = make_float2(c0A, c1A);
  *reinterpret_cast<float2*>(&gcB[q * 16 + p * 2]) = make_float2(c0B, c1B);
  wave_lds_fence();   // ONE fence for both groups
  float avgA[16], avgB[16];
#pragma unroll
  for (int j = 0; j < 4; ++j) {
    *reinterpret_cast<float4*>(&avgA[4 * j]) =
        *reinterpret_cast<const float4*>(&sm[w][0][q * 16 + 4 * j]);
    *reinterpret_cast<float4*>(&avgB[4 * j]) =
        *reinterpret_cast<const float4*>(&sm[w][1][q * 16 + 4 * j]);
  }
  wave_lds_fence();

  // ---- fused dot loop: 8 Euclid accumulators per group ----
  Dots A = {0, 0, 0, 0, 0, 0, 0, 0}, B = {0, 0, 0, 0, 0, 0, 0, 0};
#pragma unroll
  for (int i = 0; i < 16; ++i) {
    const float gyA = gm[i] * vA[i], gaA = gm[i] * avgA[i];
    A.pa = fmaf(avgA[i], avgA[i], A.pa);
    A.pd = fmaf(avgA[i], vA[i], A.pd);
    A.py = fmaf(vA[i], vA[i], A.py);
    A.Gyy = fmaf(gyA, gyA, A.Gyy);
    A.Gya = fmaf(gyA, gaA, A.Gya);
    A.Gaa = fmaf(gaA, gaA, A.Gaa);
    A.By = fmaf(bt[i], gyA, A.By);
    A.Ba = fmaf(bt[i], gaA, A.Ba);
    const float gyB = gm[i] * vB[i], gaB = gm[i] * avgB[i];
    B.pa = fmaf(avgB[i], avgB[i], B.pa);
    B.pd = fmaf(avgB[i], vB[i], B.pd);
    B.py = fmaf(vB[i], vB[i], B.py);
    B.Gyy = fmaf(gyB, gyB, B.Gyy);
    B.Gya = fmaf(gyB, gaB, B.Gya);
    B.Gaa = fmaf(gaB, gaB, B.Gaa);
    B.By = fmaf(bt[i], gyB, B.By);
    B.Ba = fmaf(bt[i], gaB, B.Ba);
  }
  // ---- one rsum round: 16 values x 3 stages over q-bits {1,2,4} ----
#pragma unroll
  for (int m = 1; m <= 4; m <<= 1) {
    A.pa += __shfl_xor(A.pa, m, 64);   B.pa += __shfl_xor(B.pa, m, 64);
    A.pd += __shfl_xor(A.pd, m, 64);   B.pd += __shfl_xor(B.pd, m, 64);
    A.py += __shfl_xor(A.py, m, 64);   B.py += __shfl_xor(B.py, m, 64);
    A.Gyy += __shfl_xor(A.Gyy, m, 64); B.Gyy += __shfl_xor(B.Gyy, m, 64);
    A.Gya += __shfl_xor(A.Gya, m, 64); B.Gya += __shfl_xor(B.Gya, m, 64);
    A.Gaa += __shfl_xor(A.Gaa, m, 64); B.Gaa += __shfl_xor(B.Gaa, m, 64);
    A.By += __shfl_xor(A.By, m, 64);   B.By += __shfl_xor(B.By, m, 64);
    A.Ba += __shfl_xor(A.Ba, m, 64);   B.Ba += __shfl_xor(B.Ba, m, 64);
  }
  const float y0A = __shfl(vA[0], lane & 56, 64);
  const float y0B = __shfl(vB[0], lane & 56, 64);
  const float avg0A = __shfl(avgA[0], 0, 64);
  const float avg0B = __shfl(avgB[0], 0, 64);
  const float gm0 = gamma[0], b0g0 = beta[0] * gamma[0];

  const int b = wid0 / S_GROUPS;
  const int s = wid0 - b * S_GROUPS;   // wid0 even, 392 even => wid0+1 same b
  chain_ep(A, y0A, avg0A, gm0, b0g0, q, p, gcA, var_part,
           (size_t)(b * 8 + p) * S_GROUPS + s);
  chain_ep(B, y0B, avg0B, gm0, b0g0, q, p, gcB, var_part,
           (size_t)(b * 8 + p) * S_GROUPS + s + 1);
}

__global__ __launch_bounds__(256) void lngn_finalize(
    const float* __restrict__ var_part, const float* __restrict__ beta,
    float* __restrict__ var_out) {
  const int wv = (int)((blockIdx.x * 256 + threadIdx.x) >> 6);  // 0..511 = b*8+p
  const int lane = threadIdx.x & 63;
  const float* base = var_part + (size_t)wv * S_GROUPS;
  float s = 0.f;
  for (int s0 = lane; s0 < S_GROUPS; s0 += 64) s += base[s0];
#pragma unroll
  for (int m = 32; m >= 1; m >>= 1) s += __shfl_xor(s, m, 64);
  if (lane == 0) var_out[wv] = s * (1.f / (float)S_GROUPS);

  // one wave additionally computes the global scalar <beta,beta>_L
  if (blockIdx.x == 0 && threadIdx.x < 64) {
    const int l = threadIdx.x;
    float b0v = beta[2 * l], b1v = beta[2 * l + 1];
    float tsum = b0v * b0v + b1v * b1v;
    if (l == 0) tsum -= 2.f * b0v * b0v;
#pragma unroll
    for (int m = 32; m >= 1; m >>= 1) tsum += __shfl_xor(tsum, m, 64);
    if (l == 0) var_out[512] = tsum;
  }
}

__global__ __launch_bounds__(256) void lngn_pass2(
    const float* __restrict__ x, const float* __restrict__ gamma,
    const float* __restrict__ beta, const float* __restrict__ var,
    const float* __restrict__ cache, float* __restrict__ out) {
  const int w = threadIdx.x >> 6, lane = threadIdx.x & 63;
  const int wid = blockIdx.x * 4 + w;
  const float* xb = x + (size_t)wid * 1024;
  const float* gc = cache + (size_t)wid * CSTRIDE;
  const int cl = lane & 31;   // channel-quad index: channels 4*cl..+3
  const int par = lane >> 5;  // pixel parity

  // wave-contiguous loads: instruction j covers bytes [j*1024 + lane*16)
  float4 xv[4];
#pragma unroll
  for (int j = 0; j < 4; ++j)
    xv[j] = *reinterpret_cast<const float4*>(xb + j * 256 + 4 * lane);
  const float4 av = *reinterpret_cast<const float4*>(gc + 4 * cl);
  const float4 gm4 = *reinterpret_cast<const float4*>(gamma + 4 * cl);
  const float4 bt4 = *reinterpret_cast<const float4*>(beta + 4 * cl);

  // per-pixel A-chain (lane computes pixel lane&7; 8-fold redundant)
  const int pix = lane & 7;
  const float4 s0 = *reinterpret_cast<const float4*>(gc + 128 + pix * 8);
  const float4 s1v = *reinterpret_cast<const float4*>(gc + 128 + pix * 8 + 4);
  const float sc = s0.x, kk = s0.y, coef = s0.z, PE = s0.w;
  const float PB = s1v.x, XT0 = s1v.y;
  const int b = wid / S_GROUPS;
  const float varv = var[b * 8 + pix];
  const float pbb = var[512];
  const float bt0 = beta[0], gm0 = gamma[0];

  const float is1 = 1.f / (varv + 1e-5f);
  const float pe = is1 * is1 * PE;
  const float pb = is1 * PB;
  const float u0 = is1 * gm0 * XT0;
  const float n = sqrtf(pe);
  const float scl = fminf(1.f, 10.f / fmaxf(n, 1e-8f));
  const float c2 = scl * pb / (1.f + bt0);
  const float uuL = pe - 2.f * u0 * u0;
  const float innw = scl * scl * uuL + 2.f * scl * c2 * (pb - u0) +
                     c2 * c2 * (pbb - 2.f * bt0 - 1.f);
  const float nrm = sqrtf(fmaxf(innw, 1e-8f));
  const float e = expf(nrm), ie = 1.f / e;
  const float chv = 0.5f * (e + ie);
  const float isn = (0.5f * (e - ie)) / nrm;
  const float A1 = chv + isn * c2;        // * beta_i
  const float Cu = isn * scl * is1;
  const float A2 = Cu * sc;               // * gamma_i * x_i
  const float A3 = Cu * kk;               // * gamma_i * avg_i
  const float A4 = fmaf(Cu * gm0, coef, isn * c2);  // += at channel 0

  float* ob = out + (size_t)wid * 1024;
#pragma unroll
  for (int j = 0; j < 4; ++j) {
    const int sp = 2 * j + par;           // pixel of this lane's j-th quad
    const float a1 = __shfl(A1, sp, 64);
    const float a2 = __shfl(A2, sp, 64);
    const float a3 = __shfl(A3, sp, 64);
    const float a4 = __shfl(A4, sp, 64);
    float4 o4;
    o4.x = fmaf(a1, bt4.x, gm4.x * fmaf(a2, xv[j].x, a3 * av.x));
    o4.y = fmaf(a1, bt4.y, gm4.y * fmaf(a2, xv[j].y, a3 * av.y));
    o4.z = fmaf(a1, bt4.z, gm4.z * fmaf(a2, xv[j].z, a3 * av.z));
    o4.w = fmaf(a1, bt4.w, gm4.w * fmaf(a2, xv[j].w, a3 * av.w));
    if (cl == 0) o4.x += a4;              // channel 0 of this pixel
    *reinterpret_cast<float4*>(ob + j * 256 + 4 * lane) = o4;
  }
}

extern "C" void kernel_launch(void* const* d_in, const int* in_sizes, int n_in,
                              void* d_out, int out_size, void* d_ws,
                              size_t ws_size, hipStream_t stream) {
  const float* x = (const float*)d_in[0];
  const float* gamma = (const float*)d_in[1];
  const float* beta = (const float*)d_in[2];
  float* out = (float*)d_out;
  float* var_part = (float*)d_ws;                      // 512*392 floats
  float* var_final = var_part + (size_t)N_GROUPS * 8;  // 513 floats (last=<b,b>_L)
  float* cache = var_part + 201472;                    // 16B-aligned, ~19.3 MB

  lngn_pass1<<<N_GROUPS / 8, 256, 0, stream>>>(x, gamma, beta, var_part, cache);
  lngn_finalize<<<128, 256, 0, stream>>>(var_part, beta, var_final);
  lngn_pass2<<<N_GROUPS / 4, 256, 0, stream>>>(x, gamma, beta, var_final, cache,
                                               out);
}

// Round 6
// 206.567 us; speedup vs baseline: 1.0618x; 1.0153x over previous
//
#include <hip/hip_runtime.h>
#include <math.h>

// LorentzNotGroupNorm, MI355X. x:(64,3136,128) fp32, groups=8.
// Group = 8 consecutive pixels x 128 ch = 4KB.
// pass1 THIS ROUND: ONE group per wave (25088 waves, 6272 blocks) -- max TLP,
// halved per-wave serial latency vs the 2-group spine. p,q layout
// (lane = 8*p+q, 16 ch/lane). Fused dot loop (8 Euclid accumulators incl
// gamma-weighted dots), one 3-stage rsum, one scalar chain (R5-verified
// algebra). Cache avg written LINEARLY (lane-ordered float2 re-read from LDS
// -> contiguous 512B store). Single wave fence (no LDS reuse).
//   pe = sc^2*Gyy + k^2*Gaa + 2sc*k*Gya + g0^2*coef*(coef+2*T0)
//   pb = sc*By + k*Ba - b0g0*(2*T0+coef)
//   na = sc^2*yy + k^2*aa + 2sc*k*ya + coef^2 + 2*coef*T0
// cache per group: avg[128] + 8 pixel-bundles{sc,k,coef,PE,PB,XT0,0,0}.
// pass2: fully elementwise, wave-contiguous (unchanged; near memory floor).

constexpr int S_GROUPS = 392;              // spatial groups per batch
constexpr int N_GROUPS = 64 * S_GROUPS;    // 25088
constexpr int CSTRIDE = 192;               // floats/group: 128 avg + 8*8 bundle

__device__ __forceinline__ void wave_lds_fence() {
  __asm__ volatile("" ::: "memory");
  __builtin_amdgcn_wave_barrier();
  __asm__ volatile("" ::: "memory");
}

// Pixel-mean fold over lane bits {32,16,8}; lane (p,q) ends with mean
// channels {16q+2p, 16q+2p+1} in (c0,c1).
__device__ __forceinline__ void fold_mean(const float v[16], int lane,
                                          float& c0, float& c1) {
  float a8[8];
  const bool h5 = (lane & 32) != 0;
#pragma unroll
  for (int i = 0; i < 8; ++i) {
    float kp = h5 ? v[i + 8] : v[i];
    float sd = h5 ? v[i] : v[i + 8];
    a8[i] = kp + __shfl_xor(sd, 32, 64);
  }
  float a4[4];
  const bool h4 = (lane & 16) != 0;
#pragma unroll
  for (int i = 0; i < 4; ++i) {
    float kp = h4 ? a8[i + 4] : a8[i];
    float sd = h4 ? a8[i] : a8[i + 4];
    a4[i] = kp + __shfl_xor(sd, 16, 64);
  }
  const bool h3 = (lane & 8) != 0;
  float kp0 = h3 ? a4[2] : a4[0], sd0 = h3 ? a4[0] : a4[2];
  float kp1 = h3 ? a4[3] : a4[1], sd1 = h3 ? a4[1] : a4[3];
  c0 = (kp0 + __shfl_xor(sd0, 8, 64)) * 0.125f;
  c1 = (kp1 + __shfl_xor(sd1, 8, 64)) * 0.125f;
}

__global__ __launch_bounds__(256) void lngn_pass1(
    const float* __restrict__ x, const float* __restrict__ gamma,
    const float* __restrict__ beta, float* __restrict__ var_part,
    float* __restrict__ cache) {
  __shared__ float sm[4][128];
  const int w = threadIdx.x >> 6, lane = threadIdx.x & 63;
  const int p = lane >> 3, q = lane & 7;
  const int wid = blockIdx.x * 4 + w;        // ONE group per wave
  const float* b0 = x + (size_t)wid * 1024 + p * 128 + q * 16;
  float* gc = cache + (size_t)wid * CSTRIDE;

  float v[16], gm[16], bt[16];
#pragma unroll
  for (int j = 0; j < 4; ++j) {
    *reinterpret_cast<float4*>(&v[4 * j]) =
        *reinterpret_cast<const float4*>(b0 + 4 * j);
    *reinterpret_cast<float4*>(&gm[4 * j]) =
        *reinterpret_cast<const float4*>(gamma + q * 16 + 4 * j);
    *reinterpret_cast<float4*>(&bt[4 * j]) =
        *reinterpret_cast<const float4*>(beta + q * 16 + 4 * j);
  }

  // fold -> LDS
  float c0, c1;
  fold_mean(v, lane, c0, c1);
  *reinterpret_cast<float2*>(&sm[w][q * 16 + p * 2]) = make_float2(c0, c1);
  wave_lds_fence();
  float avg[16];
#pragma unroll
  for (int j = 0; j < 4; ++j)
    *reinterpret_cast<float4*>(&avg[4 * j]) =
        *reinterpret_cast<const float4*>(&sm[w][q * 16 + 4 * j]);
  // linear (lane-ordered) cache write of avg: contiguous 512B per group
  const float2 t2 = *reinterpret_cast<const float2*>(&sm[w][2 * lane]);
  *reinterpret_cast<float2*>(gc + 2 * lane) = t2;

  // fused dot loop: 8 Euclid accumulators
  float pa = 0.f, pd = 0.f, py = 0.f;
  float Gyy = 0.f, Gya = 0.f, Gaa = 0.f, By = 0.f, Ba = 0.f;
#pragma unroll
  for (int i = 0; i < 16; ++i) {
    const float gy = gm[i] * v[i], ga = gm[i] * avg[i];
    pa = fmaf(avg[i], avg[i], pa);
    pd = fmaf(avg[i], v[i], pd);
    py = fmaf(v[i], v[i], py);
    Gyy = fmaf(gy, gy, Gyy);
    Gya = fmaf(gy, ga, Gya);
    Gaa = fmaf(ga, ga, Gaa);
    By = fmaf(bt[i], gy, By);
    Ba = fmaf(bt[i], ga, Ba);
  }
  // one rsum round: 8 values x 3 stages over q-bits {1,2,4}
#pragma unroll
  for (int m = 1; m <= 4; m <<= 1) {
    pa += __shfl_xor(pa, m, 64);
    pd += __shfl_xor(pd, m, 64);
    py += __shfl_xor(py, m, 64);
    Gyy += __shfl_xor(Gyy, m, 64);
    Gya += __shfl_xor(Gya, m, 64);
    Gaa += __shfl_xor(Gaa, m, 64);
    By += __shfl_xor(By, m, 64);
    Ba += __shfl_xor(Ba, m, 64);
  }
  const float y0 = __shfl(v[0], lane & 56, 64);   // y_p[0]
  const float avg0 = __shfl(avg[0], 0, 64);       // avg channel 0
  const float gm0 = gamma[0], b0g0 = beta[0] * gamma[0];

  // scalar chain (R5-verified)
  const float aaL = pa - 2.f * avg0 * avg0;
  const float rden = rsqrtf(fmaxf(-aaL, 1e-8f));
  const float mean0 = rden * avg0;
  const float yaL = pd - 2.f * avg0 * y0;
  const float yyL = py - 2.f * y0 * y0;
  const float a_raw = -yaL * rden;
  const float alpha = fmaxf(a_raw, 1.f + 1e-7f);
  const float t = alpha - 1.f;
  const float dist = log1pf(t + sqrtf(t * (alpha + 1.f)));   // arccosh
  const float inn = fmaxf(yyL + 2.f * alpha * a_raw - alpha * alpha, 1e-8f);
  const float sc = dist * rsqrtf(inn);
  const float am = alpha * rden;
  const float v0 = sc * (y0 - am * avg0);
  const float coef = -v0 / (1.f + mean0);
  const float k = coef * rden - sc * am;
  const float T0 = fmaf(sc, y0, k * avg0);
  const float na = sc * sc * py + k * k * pa + 2.f * sc * k * pd +
                   coef * coef + 2.f * coef * T0;
  const float nvar = sqrtf(fmaxf(na, 0.f));
  const float pe = sc * sc * Gyy + k * k * Gaa + 2.f * sc * k * Gya +
                   gm0 * gm0 * coef * (coef + 2.f * T0);
  const float pb = fmaf(sc, By, k * Ba) - b0g0 * (2.f * T0 + coef);
  const float XT0 = T0 + coef;

  if (q == 0) {
    *reinterpret_cast<float4*>(gc + 128 + p * 8) = make_float4(sc, k, coef, pe);
    *reinterpret_cast<float4*>(gc + 128 + p * 8 + 4) =
        make_float4(pb, XT0, 0.f, 0.f);
    const int b = wid / S_GROUPS;
    const int s = wid - b * S_GROUPS;
    var_part[(size_t)(b * 8 + p) * S_GROUPS + s] = nvar;
  }
}

__global__ __launch_bounds__(256) void lngn_finalize(
    const float* __restrict__ var_part, const float* __restrict__ beta,
    float* __restrict__ var_out) {
  const int wv = (int)((blockIdx.x * 256 + threadIdx.x) >> 6);  // 0..511 = b*8+p
  const int lane = threadIdx.x & 63;
  const float* base = var_part + (size_t)wv * S_GROUPS;
  float s = 0.f;
  for (int s0 = lane; s0 < S_GROUPS; s0 += 64) s += base[s0];
#pragma unroll
  for (int m = 32; m >= 1; m >>= 1) s += __shfl_xor(s, m, 64);
  if (lane == 0) var_out[wv] = s * (1.f / (float)S_GROUPS);

  // one wave additionally computes the global scalar <beta,beta>_L
  if (blockIdx.x == 0 && threadIdx.x < 64) {
    const int l = threadIdx.x;
    float b0v = beta[2 * l], b1v = beta[2 * l + 1];
    float tsum = b0v * b0v + b1v * b1v;
    if (l == 0) tsum -= 2.f * b0v * b0v;
#pragma unroll
    for (int m = 32; m >= 1; m >>= 1) tsum += __shfl_xor(tsum, m, 64);
    if (l == 0) var_out[512] = tsum;
  }
}

__global__ __launch_bounds__(256) void lngn_pass2(
    const float* __restrict__ x, const float* __restrict__ gamma,
    const float* __restrict__ beta, const float* __restrict__ var,
    const float* __restrict__ cache, float* __restrict__ out) {
  const int w = threadIdx.x >> 6, lane = threadIdx.x & 63;
  const int wid = blockIdx.x * 4 + w;
  const float* xb = x + (size_t)wid * 1024;
  const float* gc = cache + (size_t)wid * CSTRIDE;
  const int cl = lane & 31;   // channel-quad index: channels 4*cl..+3
  const int par = lane >> 5;  // pixel parity

  // wave-contiguous loads: instruction j covers bytes [j*1024 + lane*16)
  float4 xv[4];
#pragma unroll
  for (int j = 0; j < 4; ++j)
    xv[j] = *reinterpret_cast<const float4*>(xb + j * 256 + 4 * lane);
  const float4 av = *reinterpret_cast<const float4*>(gc + 4 * cl);
  const float4 gm4 = *reinterpret_cast<const float4*>(gamma + 4 * cl);
  const float4 bt4 = *reinterpret_cast<const float4*>(beta + 4 * cl);

  // per-pixel A-chain (lane computes pixel lane&7; 8-fold redundant)
  const int pix = lane & 7;
  const float4 s0 = *reinterpret_cast<const float4*>(gc + 128 + pix * 8);
  const float4 s1v = *reinterpret_cast<const float4*>(gc + 128 + pix * 8 + 4);
  const float sc = s0.x, kk = s0.y, coef = s0.z, PE = s0.w;
  const float PB = s1v.x, XT0 = s1v.y;
  const int b = wid / S_GROUPS;
  const float varv = var[b * 8 + pix];
  const float pbb = var[512];
  const float bt0 = beta[0], gm0 = gamma[0];

  const float is1 = 1.f / (varv + 1e-5f);
  const float pe = is1 * is1 * PE;
  const float pb = is1 * PB;
  const float u0 = is1 * gm0 * XT0;
  const float n = sqrtf(pe);
  const float scl = fminf(1.f, 10.f / fmaxf(n, 1e-8f));
  const float c2 = scl * pb / (1.f + bt0);
  const float uuL = pe - 2.f * u0 * u0;
  const float innw = scl * scl * uuL + 2.f * scl * c2 * (pb - u0) +
                     c2 * c2 * (pbb - 2.f * bt0 - 1.f);
  const float nrm = sqrtf(fmaxf(innw, 1e-8f));
  const float e = expf(nrm), ie = 1.f / e;
  const float chv = 0.5f * (e + ie);
  const float isn = (0.5f * (e - ie)) / nrm;
  const float A1 = chv + isn * c2;        // * beta_i
  const float Cu = isn * scl * is1;
  const float A2 = Cu * sc;               // * gamma_i * x_i
  const float A3 = Cu * kk;               // * gamma_i * avg_i
  const float A4 = fmaf(Cu * gm0, coef, isn * c2);  // += at channel 0

  float* ob = out + (size_t)wid * 1024;
#pragma unroll
  for (int j = 0; j < 4; ++j) {
    const int sp = 2 * j + par;           // pixel of this lane's j-th quad
    const float a1 = __shfl(A1, sp, 64);
    const float a2 = __shfl(A2, sp, 64);
    const float a3 = __shfl(A3, sp, 64);
    const float a4 = __shfl(A4, sp, 64);
    float4 o4;
    o4.x = fmaf(a1, bt4.x, gm4.x * fmaf(a2, xv[j].x, a3 * av.x));
    o4.y = fmaf(a1, bt4.y, gm4.y * fmaf(a2, xv[j].y, a3 * av.y));
    o4.z = fmaf(a1, bt4.z, gm4.z * fmaf(a2, xv[j].z, a3 * av.z));
    o4.w = fmaf(a1, bt4.w, gm4.w * fmaf(a2, xv[j].w, a3 * av.w));
    if (cl == 0) o4.x += a4;              // channel 0 of this pixel
    *reinterpret_cast<float4*>(ob + j * 256 + 4 * lane) = o4;
  }
}

extern "C" void kernel_launch(void* const* d_in, const int* in_sizes, int n_in,
                              void* d_out, int out_size, void* d_ws,
                              size_t ws_size, hipStream_t stream) {
  const float* x = (const float*)d_in[0];
  const float* gamma = (const float*)d_in[1];
  const float* beta = (const float*)d_in[2];
  float* out = (float*)d_out;
  float* var_part = (float*)d_ws;                      // 512*392 floats
  float* var_final = var_part + (size_t)N_GROUPS * 8;  // 513 floats (last=<b,b>_L)
  float* cache = var_part + 201472;                    // 16B-aligned, ~19.3 MB

  lngn_pass1<<<N_GROUPS / 4, 256, 0, stream>>>(x, gamma, beta, var_part, cache);
  lngn_finalize<<<128, 256, 0, stream>>>(var_part, beta, var_final);
  lngn_pass2<<<N_GROUPS / 4, 256, 0, stream>>>(x, gamma, beta, var_final, cache,
                                               out);
}